// Round 1
// baseline (186.115 us; speedup 1.0000x reference)
//
#include <hip/hip_runtime.h>
#include <hip/hip_bf16.h>

#define NROWS 32768
#define NFEAT 1024
#define NOUT  512

typedef __attribute__((ext_vector_type(8))) short bf16x8;   // 8 bf16 = 4 VGPR (MFMA A/B frag)
typedef __attribute__((ext_vector_type(4))) float f32x4;    // MFMA C/D frag

// ---- workspace layout ----
// [0,16)              int cnt[4]
// [256, 256+512KB)    int list[4][32768]
// [524544, +4MB)      bf16 Bt[4][512][1024]  (leaf_w transposed, K contiguous)
#define WS_CNT  0
#define WS_LIST 256
#define WS_BT   524544

// ---------------------------------------------------------------------------
// leaf_w [4][1024][512] f32  ->  Bt [4][512][1024] bf16
__global__ __launch_bounds__(256) void transpose_b_kernel(
    const float* __restrict__ lw, __hip_bfloat16* __restrict__ bt) {
  __shared__ float tile[32][33];
  int l = blockIdx.z;
  int k0 = blockIdx.x * 32;  // feature dim (1024)
  int d0 = blockIdx.y * 32;  // output dim (512)
  int x = threadIdx.x;       // 0..31
  int y = threadIdx.y;       // 0..7
  const float* src = lw + (size_t)l * NFEAT * NOUT;
#pragma unroll
  for (int i = 0; i < 4; ++i)
    tile[y * 4 + i][x] = src[(size_t)(k0 + y * 4 + i) * NOUT + d0 + x];
  __syncthreads();
  __hip_bfloat16* dst = bt + (size_t)l * NOUT * NFEAT;
#pragma unroll
  for (int i = 0; i < 4; ++i)
    dst[(size_t)(d0 + y * 4 + i) * NFEAT + k0 + x] = __float2bfloat16(tile[x][y * 4 + i]);
}

// ---------------------------------------------------------------------------
// fp32 decisions + compacted per-leaf row lists.
// 256 threads = 4 waves; wave handles 16 rows (64 rows/block); grid = 512.
__global__ __launch_bounds__(256) void decide_kernel(
    const float* __restrict__ xs, const float* __restrict__ dw,
    const float* __restrict__ db, int* __restrict__ cnt, int* __restrict__ list) {
  const int tid = threadIdx.x;
  const int lane = tid & 63;
  const int wv = tid >> 6;
  __shared__ int leaf_of[64];

  // decision weights held in registers, reused for 16 rows
  f32x4 w0[4], w1[4], w2[4];
#pragma unroll
  for (int c = 0; c < 4; ++c) {
    int idx = c * 256 + lane * 4;
    w0[c] = *(const f32x4*)(dw + idx);
    w1[c] = *(const f32x4*)(dw + NFEAT + idx);
    w2[c] = *(const f32x4*)(dw + 2 * NFEAT + idx);
  }
  float b0 = db[0], b1 = db[1], b2 = db[2];

  int rowbase = blockIdx.x * 64 + wv * 16;
  for (int r = 0; r < 16; ++r) {
    const float* xr = xs + (size_t)(rowbase + r) * NFEAT;
    float s0 = 0.f, s1 = 0.f, s2 = 0.f;
#pragma unroll
    for (int c = 0; c < 4; ++c) {
      int idx = c * 256 + lane * 4;
      f32x4 xv = *(const f32x4*)(xr + idx);
#pragma unroll
      for (int j = 0; j < 4; ++j) {
        s0 += xv[j] * w0[c][j];
        s1 += xv[j] * w1[c][j];
        s2 += xv[j] * w2[c][j];
      }
    }
#pragma unroll
    for (int off = 32; off > 0; off >>= 1) {
      s0 += __shfl_xor(s0, off);
      s1 += __shfl_xor(s1, off);
      s2 += __shfl_xor(s2, off);
    }
    if (lane == 0) {
      int lf = (s0 + b0 > 0.f) ? ((s2 + b2 > 0.f) ? 3 : 2)
                               : ((s1 + b1 > 0.f) ? 1 : 0);
      leaf_of[wv * 16 + r] = lf;
    }
  }
  __syncthreads();

  // wave 0: ballot-rank compaction, 4 atomics per block
  if (tid < 64) {
    int i = tid;
    int myleaf = leaf_of[i];
    int myrow = blockIdx.x * 64 + i;
    unsigned long long m0 = __ballot(myleaf == 0);
    unsigned long long m1 = __ballot(myleaf == 1);
    unsigned long long m2 = __ballot(myleaf == 2);
    unsigned long long m3 = __ballot(myleaf == 3);
    unsigned long long mym = (myleaf == 0) ? m0 : (myleaf == 1) ? m1
                           : (myleaf == 2) ? m2 : m3;
    unsigned long long below = (1ull << i) - 1ull;
    int rank = __popcll(mym & below);
    int base = 0;
    if (i < 4) {
      unsigned long long mi = (i == 0) ? m0 : (i == 1) ? m1 : (i == 2) ? m2 : m3;
      base = atomicAdd(&cnt[i], __popcll(mi));
    }
    int mybase = __shfl(base, myleaf);
    list[myleaf * NROWS + mybase + rank] = myrow;
  }
}

// ---------------------------------------------------------------------------
// Grouped GEMM: out[row] = bf16(xs[row]) @ bf16(leaf_w[leaf]) + leaf_b[leaf]
// BM=128 gathered rows, BN=128, BK=64, 256 threads (4 waves of 64x64).
#define BM 128
#define BN 128
#define BK 64
#define KSTEPS (NFEAT / BK)

__global__ __launch_bounds__(256) void gemm_kernel(
    const float* __restrict__ xs, const __hip_bfloat16* __restrict__ bt,
    const float* __restrict__ lb, const int* __restrict__ cnt,
    const int* __restrict__ list, float* __restrict__ out) {
  __shared__ __hip_bfloat16 Al[BM * BK];  // [row][granule^ (row&7)] 16B granules
  __shared__ __hip_bfloat16 Bl[BN * BK];
  __shared__ int rows_s[BM];

  // bijective XCD swizzle (grid = 1040 = 8*130): siblings share an XCD
  int bid = blockIdx.x;
  int cpx = (int)(gridDim.x >> 3);
  int swz = (bid & 7) * cpx + (bid >> 3);
  int mtile = swz >> 2;
  int ntile = swz & 3;

  int c0 = cnt[0], c1 = cnt[1], c2 = cnt[2], c3 = cnt[3];
  int t0 = (c0 + BM - 1) / BM, t1 = (c1 + BM - 1) / BM;
  int t2 = (c2 + BM - 1) / BM, t3 = (c3 + BM - 1) / BM;
  int leaf, mloc, cc;
  if (mtile < t0)                     { leaf = 0; mloc = mtile;                cc = c0; }
  else if (mtile < t0 + t1)           { leaf = 1; mloc = mtile - t0;           cc = c1; }
  else if (mtile < t0 + t1 + t2)      { leaf = 2; mloc = mtile - t0 - t1;      cc = c2; }
  else if (mtile < t0 + t1 + t2 + t3) { leaf = 3; mloc = mtile - t0 - t1 - t2; cc = c3; }
  else return;

  const int tid = threadIdx.x;
  if (tid < BM) {
    int i = mloc * BM + tid;
    rows_s[tid] = (i < cc) ? list[leaf * NROWS + i] : -1;
  }
  __syncthreads();

  // staging assignment: 2 threads per row, each covers a 32-k half
  const int srow = tid >> 1;
  const int shalf = tid & 1;
  int a_grow = rows_s[srow];
  int a_clamp = (a_grow < 0) ? 0 : a_grow;  // padded rows load row 0; result discarded
  const float* aptr = xs + (size_t)a_clamp * NFEAT + shalf * 32;
  const __hip_bfloat16* bptr =
      bt + ((size_t)leaf * NOUT + ntile * BN + srow) * NFEAT + shalf * 32;

  const int lane = tid & 63;
  const int wv = tid >> 6;
  const int wr = (wv >> 1) * 64;
  const int wc = (wv & 1) * 64;

  f32x4 acc[4][4];
#pragma unroll
  for (int m = 0; m < 4; ++m)
#pragma unroll
    for (int n = 0; n < 4; ++n) acc[m][n] = (f32x4){0.f, 0.f, 0.f, 0.f};

  f32x4 av[8];
  bf16x8 bv[4];
#define LOAD_TILE(K0)                                                        \
  {                                                                          \
    _Pragma("unroll") for (int j = 0; j < 8; ++j)                            \
        av[j] = *(const f32x4*)(aptr + (K0) + j * 4);                        \
    _Pragma("unroll") for (int j = 0; j < 4; ++j)                            \
        bv[j] = *(const bf16x8*)(bptr + (K0) + j * 8);                       \
  }

  LOAD_TILE(0);

  for (int ks = 0; ks < KSTEPS; ++ks) {
    // ---- ds_write current tile (f32 -> bf16 for A) ----
#pragma unroll
    for (int j = 0; j < 4; ++j) {
      union { bf16x8 v; __hip_bfloat16 h[8]; } pk;
#pragma unroll
      for (int e = 0; e < 8; ++e)
        pk.h[e] = __float2bfloat16(av[j * 2 + (e >> 2)][e & 3]);
      int g = shalf * 4 + j;
      *(bf16x8*)(&Al[srow * BK + ((g ^ (srow & 7)) << 3)]) = pk.v;
    }
#pragma unroll
    for (int j = 0; j < 4; ++j) {
      int g = shalf * 4 + j;
      *(bf16x8*)(&Bl[srow * BK + ((g ^ (srow & 7)) << 3)]) = bv[j];
    }
    __syncthreads();

    // ---- issue next tile's global loads (land during MFMA) ----
    if (ks + 1 < KSTEPS) LOAD_TILE((ks + 1) * BK);

    // ---- MFMA on LDS tile ----
#pragma unroll
    for (int kk = 0; kk < 2; ++kk) {
      bf16x8 af[4], bfr[4];
      int gk = kk * 4 + (lane >> 4);
#pragma unroll
      for (int m = 0; m < 4; ++m) {
        int r = wr + m * 16 + (lane & 15);
        af[m] = *(const bf16x8*)(&Al[r * BK + ((gk ^ (r & 7)) << 3)]);
      }
#pragma unroll
      for (int n = 0; n < 4; ++n) {
        int r = wc + n * 16 + (lane & 15);
        bfr[n] = *(const bf16x8*)(&Bl[r * BK + ((gk ^ (r & 7)) << 3)]);
      }
#pragma unroll
      for (int m = 0; m < 4; ++m)
#pragma unroll
        for (int n = 0; n < 4; ++n)
          acc[m][n] = __builtin_amdgcn_mfma_f32_16x16x32_bf16(
              af[m], bfr[n], acc[m][n], 0, 0, 0);
    }
    __syncthreads();
  }

  // ---- epilogue: bias + scattered row store ----
  int colb = ntile * BN + wc;
#pragma unroll
  for (int n = 0; n < 4; ++n) {
    int col = colb + n * 16 + (lane & 15);
    float bias = lb[leaf * NOUT + col];
#pragma unroll
    for (int m = 0; m < 4; ++m) {
#pragma unroll
      for (int r = 0; r < 4; ++r) {
        int lrow = wr + m * 16 + (lane >> 4) * 4 + r;
        int grow = rows_s[lrow];
        if (grow >= 0) out[(size_t)grow * NOUT + col] = acc[m][n][r] + bias;
      }
    }
  }
}

// ---------------------------------------------------------------------------
extern "C" void kernel_launch(void* const* d_in, const int* in_sizes, int n_in,
                              void* d_out, int out_size, void* d_ws, size_t ws_size,
                              hipStream_t stream) {
  const float* xs = (const float*)d_in[0];
  const float* dw = (const float*)d_in[1];
  const float* db = (const float*)d_in[2];
  const float* lw = (const float*)d_in[3];
  const float* lb = (const float*)d_in[4];
  float* out = (float*)d_out;
  char* ws = (char*)d_ws;
  int* cnt = (int*)(ws + WS_CNT);
  int* list = (int*)(ws + WS_LIST);
  __hip_bfloat16* bt = (__hip_bfloat16*)(ws + WS_BT);

  hipMemsetAsync(cnt, 0, 4 * sizeof(int), stream);
  transpose_b_kernel<<<dim3(32, 16, 4), dim3(32, 8), 0, stream>>>(lw, bt);
  decide_kernel<<<512, 256, 0, stream>>>(xs, dw, db, cnt, list);
  // max M-tiles = sum ceil(cnt_k/128) <= 260; grid = 260*4 N-tiles = 1040 = 8*130
  gemm_kernel<<<1040, 256, 0, stream>>>(xs, bt, lb, cnt, list, out);
}

// Round 2
// 128.624 us; speedup vs baseline: 1.4470x; 1.4470x over previous
//
#include <hip/hip_runtime.h>
#include <hip/hip_bf16.h>
#include <stdint.h>

#define NROWS 32768
#define NFEAT 1024
#define NOUT  512

typedef __attribute__((ext_vector_type(8))) short bf16x8;   // 8 bf16 (4 VGPR)
typedef __attribute__((ext_vector_type(4))) short bf16x4;   // 4 bf16 (8 B)
typedef __attribute__((ext_vector_type(4))) float f32x4;    // MFMA C/D frag

// ---- workspace layout ----
// [0,16)        int cnt[4]
// [256, +512KB) int list[4][32768]
// [524544, +4MB) bf16 Bt[4][512][1024]   (leaf_w transposed, K contiguous)
// [4718848, +64MB) bf16 xsb[32768][1024] (xs converted)
#define WS_CNT  0
#define WS_LIST 256
#define WS_BT   524544
#define WS_XB   (WS_BT + (size_t)4 * NOUT * NFEAT * 2)
#define WS_NEEDED (WS_XB + (size_t)NROWS * NFEAT * 2)

// ---------------------------------------------------------------------------
// leaf_w [4][1024][512] f32  ->  Bt [4][512][1024] bf16
__global__ __launch_bounds__(256) void transpose_b_kernel(
    const float* __restrict__ lw, __hip_bfloat16* __restrict__ bt) {
  __shared__ float tile[32][33];
  int l = blockIdx.z;
  int k0 = blockIdx.x * 32;
  int d0 = blockIdx.y * 32;
  int x = threadIdx.x;
  int y = threadIdx.y;
  const float* src = lw + (size_t)l * NFEAT * NOUT;
#pragma unroll
  for (int i = 0; i < 4; ++i)
    tile[y * 4 + i][x] = src[(size_t)(k0 + y * 4 + i) * NOUT + d0 + x];
  __syncthreads();
  __hip_bfloat16* dst = bt + (size_t)l * NOUT * NFEAT;
#pragma unroll
  for (int i = 0; i < 4; ++i)
    dst[(size_t)(d0 + y * 4 + i) * NFEAT + k0 + x] = __float2bfloat16(tile[x][y * 4 + i]);
}

// ---------------------------------------------------------------------------
// fp32 decisions + compacted per-leaf row lists + fused xs->bf16 conversion.
// 256 threads = 4 waves; wave handles 16 rows; grid = 512.
__global__ __launch_bounds__(256) void decide_kernel(
    const float* __restrict__ xs, const float* __restrict__ dw,
    const float* __restrict__ db, int* __restrict__ cnt, int* __restrict__ list,
    __hip_bfloat16* __restrict__ xsb /* may be null */) {
  const int tid = threadIdx.x;
  const int lane = tid & 63;
  const int wv = tid >> 6;
  __shared__ int leaf_of[64];

  f32x4 w0[4], w1[4], w2[4];
#pragma unroll
  for (int c = 0; c < 4; ++c) {
    int idx = c * 256 + lane * 4;
    w0[c] = *(const f32x4*)(dw + idx);
    w1[c] = *(const f32x4*)(dw + NFEAT + idx);
    w2[c] = *(const f32x4*)(dw + 2 * NFEAT + idx);
  }
  float b0 = db[0], b1 = db[1], b2 = db[2];

  int rowbase = blockIdx.x * 64 + wv * 16;
  for (int r = 0; r < 16; ++r) {
    int row = rowbase + r;
    const float* xr = xs + (size_t)row * NFEAT;
    float s0 = 0.f, s1 = 0.f, s2 = 0.f;
#pragma unroll
    for (int c = 0; c < 4; ++c) {
      int idx = c * 256 + lane * 4;
      f32x4 xv = *(const f32x4*)(xr + idx);
#pragma unroll
      for (int j = 0; j < 4; ++j) {
        s0 += xv[j] * w0[c][j];
        s1 += xv[j] * w1[c][j];
        s2 += xv[j] * w2[c][j];
      }
      if (xsb) {
        union { bf16x4 v; __hip_bfloat16 h[4]; } pk;
#pragma unroll
        for (int j = 0; j < 4; ++j) pk.h[j] = __float2bfloat16(xv[j]);
        *(bf16x4*)(xsb + (size_t)row * NFEAT + idx) = pk.v;
      }
    }
#pragma unroll
    for (int off = 32; off > 0; off >>= 1) {
      s0 += __shfl_xor(s0, off);
      s1 += __shfl_xor(s1, off);
      s2 += __shfl_xor(s2, off);
    }
    if (lane == 0) {
      int lf = (s0 + b0 > 0.f) ? ((s2 + b2 > 0.f) ? 3 : 2)
                               : ((s1 + b1 > 0.f) ? 1 : 0);
      leaf_of[wv * 16 + r] = lf;
    }
  }
  __syncthreads();

  if (tid < 64) {
    int i = tid;
    int myleaf = leaf_of[i];
    int myrow = blockIdx.x * 64 + i;
    unsigned long long m0 = __ballot(myleaf == 0);
    unsigned long long m1 = __ballot(myleaf == 1);
    unsigned long long m2 = __ballot(myleaf == 2);
    unsigned long long m3 = __ballot(myleaf == 3);
    unsigned long long mym = (myleaf == 0) ? m0 : (myleaf == 1) ? m1
                           : (myleaf == 2) ? m2 : m3;
    unsigned long long below = (1ull << i) - 1ull;
    int rank = __popcll(mym & below);
    int base = 0;
    if (i < 4) {
      unsigned long long mi = (i == 0) ? m0 : (i == 1) ? m1 : (i == 2) ? m2 : m3;
      base = atomicAdd(&cnt[i], __popcll(mi));
    }
    int mybase = __shfl(base, myleaf);
    list[myleaf * NROWS + mybase + rank] = myrow;
  }
}

// ---------------------------------------------------------------------------
#define BM 128
#define BN 128
#define BK 64
#define KSTEPS (NFEAT / BK)

// Shared tile decode: block id -> (leaf, mloc, ntile); returns false if idle.
__device__ __forceinline__ bool decode_tile(const int* cnt, int& leaf, int& mloc,
                                            int& ntile, int& cc) {
  int bid = blockIdx.x;
  int cpx = (int)(gridDim.x >> 3);
  int swz = (bid & 7) * cpx + (bid >> 3);
  int mtile = swz >> 2;
  ntile = swz & 3;
  int c0 = cnt[0], c1 = cnt[1], c2 = cnt[2], c3 = cnt[3];
  int t0 = (c0 + BM - 1) / BM, t1 = (c1 + BM - 1) / BM;
  int t2 = (c2 + BM - 1) / BM, t3 = (c3 + BM - 1) / BM;
  if (mtile < t0)                     { leaf = 0; mloc = mtile;                cc = c0; }
  else if (mtile < t0 + t1)           { leaf = 1; mloc = mtile - t0;           cc = c1; }
  else if (mtile < t0 + t1 + t2)      { leaf = 2; mloc = mtile - t0 - t1;      cc = c2; }
  else if (mtile < t0 + t1 + t2 + t3) { leaf = 3; mloc = mtile - t0 - t1 - t2; cc = c3; }
  else return false;
  return true;
}

// m97-structure grouped GEMM: global_load_lds staging, linear LDS dest,
// inverse-XOR-swizzled per-lane global source, XOR-swizzled ds_read.
__global__ __launch_bounds__(256) void gemm_lds_kernel(
    const __hip_bfloat16* __restrict__ xsb, const __hip_bfloat16* __restrict__ bt,
    const float* __restrict__ lb, const int* __restrict__ cnt,
    const int* __restrict__ list, float* __restrict__ out) {
  __shared__ __hip_bfloat16 Al[BM * BK];  // LDS[r][g] = A[row_r][g ^ (r&7)] (16B granules)
  __shared__ __hip_bfloat16 Bl[BN * BK];
  __shared__ int rows_s[BM];

  int leaf, mloc, ntile, cc;
  if (!decode_tile(cnt, leaf, mloc, ntile, cc)) return;

  const int tid = threadIdx.x;
  if (tid < BM) {
    int i = mloc * BM + tid;
    rows_s[tid] = (i < cc) ? list[leaf * NROWS + i] : -1;
  }
  __syncthreads();

  const int lane = tid & 63;
  const int wv = tid >> 6;
  // staging: chunk c = wv*4+j covers tile rows c*8..c*8+7 (1 KB LDS each).
  // lane l -> row c*8 + (l>>3), LDS granule l&7; source granule = (l&7)^(l>>3)
  // (row&7 == l>>3 since c*8 is a multiple of 8).
  const int g8 = (((lane & 7) ^ (lane >> 3)) << 3);  // element offset in row
  const __hip_bfloat16* asrc[4];
  const __hip_bfloat16* bsrc[4];
#pragma unroll
  for (int j = 0; j < 4; ++j) {
    int tr = wv * 32 + j * 8 + (lane >> 3);
    int grow = rows_s[tr];
    if (grow < 0) grow = 0;  // padded rows: load row 0, result discarded
    asrc[j] = xsb + (size_t)grow * NFEAT + g8;
    bsrc[j] = bt + ((size_t)leaf * NOUT + ntile * BN + tr) * NFEAT + g8;
  }

  const int wr = (wv >> 1) * 64;
  const int wc = (wv & 1) * 64;
  f32x4 acc[4][4];
#pragma unroll
  for (int m = 0; m < 4; ++m)
#pragma unroll
    for (int n = 0; n < 4; ++n) acc[m][n] = (f32x4){0.f, 0.f, 0.f, 0.f};

  for (int ks = 0; ks < KSTEPS; ++ks) {
    if (ks) __syncthreads();  // all waves done reading LDS before overwrite
#pragma unroll
    for (int j = 0; j < 4; ++j) {
      __builtin_amdgcn_global_load_lds(
          (const __attribute__((address_space(1))) void*)(asrc[j] + ks * BK),
          (__attribute__((address_space(3))) void*)(&Al[(wv * 4 + j) * 512]),
          16, 0, 0);
      __builtin_amdgcn_global_load_lds(
          (const __attribute__((address_space(1))) void*)(bsrc[j] + ks * BK),
          (__attribute__((address_space(3))) void*)(&Bl[(wv * 4 + j) * 512]),
          16, 0, 0);
    }
    __syncthreads();  // drains vmcnt(0): tile resident

#pragma unroll
    for (int kk = 0; kk < 2; ++kk) {
      bf16x8 af[4], bfr[4];
      int gk = kk * 4 + (lane >> 4);
#pragma unroll
      for (int m = 0; m < 4; ++m) {
        int r = wr + m * 16 + (lane & 15);
        af[m] = *(const bf16x8*)(&Al[r * BK + ((gk ^ (r & 7)) << 3)]);
      }
#pragma unroll
      for (int n = 0; n < 4; ++n) {
        int r = wc + n * 16 + (lane & 15);
        bfr[n] = *(const bf16x8*)(&Bl[r * BK + ((gk ^ (r & 7)) << 3)]);
      }
#pragma unroll
      for (int m = 0; m < 4; ++m)
#pragma unroll
        for (int n = 0; n < 4; ++n)
          acc[m][n] = __builtin_amdgcn_mfma_f32_16x16x32_bf16(
              af[m], bfr[n], acc[m][n], 0, 0, 0);
    }
  }

  int colb = ntile * BN + wc;
#pragma unroll
  for (int n = 0; n < 4; ++n) {
    int col = colb + n * 16 + (lane & 15);
    float bias = lb[leaf * NOUT + col];
#pragma unroll
    for (int m = 0; m < 4; ++m) {
#pragma unroll
      for (int r = 0; r < 4; ++r) {
        int lrow = wr + m * 16 + (lane >> 4) * 4 + r;
        int grow = rows_s[lrow];
        if (grow >= 0) out[(size_t)grow * NOUT + col] = acc[m][n][r] + bias;
      }
    }
  }
}

// ---------------------------------------------------------------------------
// Fallback GEMM (round-1 reg-staging, f32 A with on-the-fly cvt) — used only
// if ws_size is too small for the xs-bf16 buffer.
__global__ __launch_bounds__(256) void gemm_fallback_kernel(
    const float* __restrict__ xs, const __hip_bfloat16* __restrict__ bt,
    const float* __restrict__ lb, const int* __restrict__ cnt,
    const int* __restrict__ list, float* __restrict__ out) {
  __shared__ __hip_bfloat16 Al[BM * BK];
  __shared__ __hip_bfloat16 Bl[BN * BK];
  __shared__ int rows_s[BM];

  int leaf, mloc, ntile, cc;
  if (!decode_tile(cnt, leaf, mloc, ntile, cc)) return;

  const int tid = threadIdx.x;
  if (tid < BM) {
    int i = mloc * BM + tid;
    rows_s[tid] = (i < cc) ? list[leaf * NROWS + i] : -1;
  }
  __syncthreads();

  const int srow = tid >> 1;
  const int shalf = tid & 1;
  int a_grow = rows_s[srow];
  int a_clamp = (a_grow < 0) ? 0 : a_grow;
  const float* aptr = xs + (size_t)a_clamp * NFEAT + shalf * 32;
  const __hip_bfloat16* bptr =
      bt + ((size_t)leaf * NOUT + ntile * BN + srow) * NFEAT + shalf * 32;

  const int lane = tid & 63;
  const int wv = tid >> 6;
  const int wr = (wv >> 1) * 64;
  const int wc = (wv & 1) * 64;

  f32x4 acc[4][4];
#pragma unroll
  for (int m = 0; m < 4; ++m)
#pragma unroll
    for (int n = 0; n < 4; ++n) acc[m][n] = (f32x4){0.f, 0.f, 0.f, 0.f};

  f32x4 av[8];
  bf16x8 bv[4];
#define LOAD_TILE(K0)                                                        \
  {                                                                          \
    _Pragma("unroll") for (int j = 0; j < 8; ++j)                            \
        av[j] = *(const f32x4*)(aptr + (K0) + j * 4);                        \
    _Pragma("unroll") for (int j = 0; j < 4; ++j)                            \
        bv[j] = *(const bf16x8*)(bptr + (K0) + j * 8);                       \
  }

  LOAD_TILE(0);

  for (int ks = 0; ks < KSTEPS; ++ks) {
#pragma unroll
    for (int j = 0; j < 4; ++j) {
      union { bf16x8 v; __hip_bfloat16 h[8]; } pk;
#pragma unroll
      for (int e = 0; e < 8; ++e)
        pk.h[e] = __float2bfloat16(av[j * 2 + (e >> 2)][e & 3]);
      int g = shalf * 4 + j;
      *(bf16x8*)(&Al[srow * BK + ((g ^ (srow & 7)) << 3)]) = pk.v;
    }
#pragma unroll
    for (int j = 0; j < 4; ++j) {
      int g = shalf * 4 + j;
      *(bf16x8*)(&Bl[srow * BK + ((g ^ (srow & 7)) << 3)]) = bv[j];
    }
    __syncthreads();

    if (ks + 1 < KSTEPS) LOAD_TILE((ks + 1) * BK);

#pragma unroll
    for (int kk = 0; kk < 2; ++kk) {
      bf16x8 af[4], bfr[4];
      int gk = kk * 4 + (lane >> 4);
#pragma unroll
      for (int m = 0; m < 4; ++m) {
        int r = wr + m * 16 + (lane & 15);
        af[m] = *(const bf16x8*)(&Al[r * BK + ((gk ^ (r & 7)) << 3)]);
      }
#pragma unroll
      for (int n = 0; n < 4; ++n) {
        int r = wc + n * 16 + (lane & 15);
        bfr[n] = *(const bf16x8*)(&Bl[r * BK + ((gk ^ (r & 7)) << 3)]);
      }
#pragma unroll
      for (int m = 0; m < 4; ++m)
#pragma unroll
        for (int n = 0; n < 4; ++n)
          acc[m][n] = __builtin_amdgcn_mfma_f32_16x16x32_bf16(
              af[m], bfr[n], acc[m][n], 0, 0, 0);
    }
    __syncthreads();
  }

  int colb = ntile * BN + wc;
#pragma unroll
  for (int n = 0; n < 4; ++n) {
    int col = colb + n * 16 + (lane & 15);
    float bias = lb[leaf * NOUT + col];
#pragma unroll
    for (int m = 0; m < 4; ++m) {
#pragma unroll
      for (int r = 0; r < 4; ++r) {
        int lrow = wr + m * 16 + (lane >> 4) * 4 + r;
        int grow = rows_s[lrow];
        if (grow >= 0) out[(size_t)grow * NOUT + col] = acc[m][n][r] + bias;
      }
    }
  }
}

// ---------------------------------------------------------------------------
extern "C" void kernel_launch(void* const* d_in, const int* in_sizes, int n_in,
                              void* d_out, int out_size, void* d_ws, size_t ws_size,
                              hipStream_t stream) {
  const float* xs = (const float*)d_in[0];
  const float* dw = (const float*)d_in[1];
  const float* db = (const float*)d_in[2];
  const float* lw = (const float*)d_in[3];
  const float* lb = (const float*)d_in[4];
  float* out = (float*)d_out;
  char* ws = (char*)d_ws;
  int* cnt = (int*)(ws + WS_CNT);
  int* list = (int*)(ws + WS_LIST);
  __hip_bfloat16* bt = (__hip_bfloat16*)(ws + WS_BT);
  bool big = ws_size >= WS_NEEDED;
  __hip_bfloat16* xsb = big ? (__hip_bfloat16*)(ws + WS_XB) : nullptr;

  hipMemsetAsync(cnt, 0, 4 * sizeof(int), stream);
  transpose_b_kernel<<<dim3(32, 16, 4), dim3(32, 8), 0, stream>>>(lw, bt);
  decide_kernel<<<512, 256, 0, stream>>>(xs, dw, db, cnt, list, xsb);
  // max M-tiles = sum ceil(cnt_k/128) <= 260; grid = 260*4 = 1040 = 8*130
  if (big)
    gemm_lds_kernel<<<1040, 256, 0, stream>>>(xsb, bt, lb, cnt, list, out);
  else
    gemm_fallback_kernel<<<1040, 256, 0, stream>>>(xs, bt, lb, cnt, list, out);
}

// Round 3
// 105.901 us; speedup vs baseline: 1.7574x; 1.2146x over previous
//
#include <hip/hip_runtime.h>
#include <hip/hip_bf16.h>
#include <stdint.h>

#define NROWS 32768
#define NFEAT 1024
#define NOUT  512

typedef __attribute__((ext_vector_type(8))) short bf16x8;   // 8 bf16 (4 VGPR)
typedef __attribute__((ext_vector_type(4))) float f32x4;    // MFMA C/D frag

// ---- workspace layout ----
// [0,16)        int cnt[4]
// [256, +512KB) int list[4][32768]
// [524544, +4MB) bf16 Bt[4][512][1024]   (leaf_w transposed, K contiguous)
// [4718848, +64MB) bf16 xsb[32768][1024] (xs converted)
#define WS_CNT  0
#define WS_LIST 256
#define WS_BT   524544
#define WS_XB   (WS_BT + (size_t)4 * NOUT * NFEAT * 2)
#define WS_NEEDED (WS_XB + (size_t)NROWS * NFEAT * 2)

#define NDEC_BLOCKS 1024   // 32 rows each
#define NTR_BLOCKS  512    // 4 k-subtiles of 32x32 each

// ---------------------------------------------------------------------------
__global__ __launch_bounds__(64) void zero_cnt_kernel(int* __restrict__ cnt) {
  if (threadIdx.x < 4) cnt[threadIdx.x] = 0;
}

// ---------------------------------------------------------------------------
// Fused: fp32 decisions + compaction + xs->bf16 conversion (blocks [0,1024))
//        and leaf_w transpose->bf16 (blocks [1024, 1536)).
__global__ __launch_bounds__(256) void decide_tr_kernel(
    const float* __restrict__ xs, const float* __restrict__ dw,
    const float* __restrict__ db, const float* __restrict__ lw,
    __hip_bfloat16* __restrict__ bt, int* __restrict__ cnt,
    int* __restrict__ list, __hip_bfloat16* __restrict__ xsb /* may be null */) {
  __shared__ float smem[32 * 33];
  const int tid = threadIdx.x;
  int b = blockIdx.x;

  if (b >= NDEC_BLOCKS) {
    // ---- transpose part: leaf_w [4][1024][512] f32 -> Bt [4][512][1024] bf16
    int tb = b - NDEC_BLOCKS;           // [0,512)
    int l = tb >> 7;                    // leaf
    int t = tb & 127;                   // 16 d-tiles x 8 k-groups
    int d0 = (t >> 3) * 32;
    int k00 = (t & 7) * 128;
    int x = tid & 31, y = tid >> 5;     // (32,8)
    const float* src = lw + (size_t)l * NFEAT * NOUT;
    __hip_bfloat16* dst = bt + (size_t)l * NOUT * NFEAT;
    float (*tile)[33] = (float(*)[33])smem;
    for (int kk = 0; kk < 4; ++kk) {
      int k0 = k00 + kk * 32;
#pragma unroll
      for (int i = 0; i < 4; ++i)
        tile[y * 4 + i][x] = src[(size_t)(k0 + y * 4 + i) * NOUT + d0 + x];
      __syncthreads();
#pragma unroll
      for (int i = 0; i < 4; ++i)
        dst[(size_t)(d0 + y * 4 + i) * NFEAT + k0 + x] =
            __float2bfloat16(tile[x][y * 4 + i]);
      __syncthreads();
    }
    return;
  }

  // ---- decide part: 32 rows/block, 8 rows/wave, lane covers 8 features x 2 chunks
  int* leaf_of = (int*)smem;
  const int lane = tid & 63;
  const int wv = tid >> 6;

  // w[d][c*2+h]: features c*512 + lane*8 + h*4
  f32x4 w0[4], w1[4], w2[4];
#pragma unroll
  for (int c = 0; c < 2; ++c)
#pragma unroll
    for (int h = 0; h < 2; ++h) {
      int idx = c * 512 + lane * 8 + h * 4;
      w0[c * 2 + h] = *(const f32x4*)(dw + idx);
      w1[c * 2 + h] = *(const f32x4*)(dw + NFEAT + idx);
      w2[c * 2 + h] = *(const f32x4*)(dw + 2 * NFEAT + idx);
    }
  float b0 = db[0], b1 = db[1], b2 = db[2];

  int rowbase = b * 32 + wv * 8;
  for (int r = 0; r < 8; ++r) {
    int row = rowbase + r;
    const float* xr = xs + (size_t)row * NFEAT;
    float s0 = 0.f, s1 = 0.f, s2 = 0.f;
#pragma unroll
    for (int c = 0; c < 2; ++c) {
      int idx = c * 512 + lane * 8;
      f32x4 xv0 = *(const f32x4*)(xr + idx);
      f32x4 xv1 = *(const f32x4*)(xr + idx + 4);
#pragma unroll
      for (int j = 0; j < 4; ++j) {
        s0 += xv0[j] * w0[c * 2][j] + xv1[j] * w0[c * 2 + 1][j];
        s1 += xv0[j] * w1[c * 2][j] + xv1[j] * w1[c * 2 + 1][j];
        s2 += xv0[j] * w2[c * 2][j] + xv1[j] * w2[c * 2 + 1][j];
      }
      if (xsb) {
        union { bf16x8 v; __hip_bfloat16 h[8]; } pk;
#pragma unroll
        for (int j = 0; j < 4; ++j) {
          pk.h[j] = __float2bfloat16(xv0[j]);
          pk.h[j + 4] = __float2bfloat16(xv1[j]);
        }
        *(bf16x8*)(xsb + (size_t)row * NFEAT + idx) = pk.v;
      }
    }
#pragma unroll
    for (int off = 32; off > 0; off >>= 1) {
      s0 += __shfl_xor(s0, off);
      s1 += __shfl_xor(s1, off);
      s2 += __shfl_xor(s2, off);
    }
    if (lane == 0) {
      int lf = (s0 + b0 > 0.f) ? ((s2 + b2 > 0.f) ? 3 : 2)
                               : ((s1 + b1 > 0.f) ? 1 : 0);
      leaf_of[wv * 8 + r] = lf;
    }
  }
  __syncthreads();

  // wave 0: ballot-rank compaction over the 32 rows, 4 atomics per block
  if (tid < 64) {
    int i = tid;
    int myleaf = (i < 32) ? leaf_of[i] : -1;
    int myrow = b * 32 + i;
    unsigned long long m0 = __ballot(myleaf == 0);
    unsigned long long m1 = __ballot(myleaf == 1);
    unsigned long long m2 = __ballot(myleaf == 2);
    unsigned long long m3 = __ballot(myleaf == 3);
    unsigned long long mym = (myleaf == 0) ? m0 : (myleaf == 1) ? m1
                           : (myleaf == 2) ? m2 : (myleaf == 3) ? m3 : 0ull;
    unsigned long long below = (1ull << i) - 1ull;
    int rank = __popcll(mym & below);
    int base = 0;
    if (i < 4) {
      unsigned long long mi = (i == 0) ? m0 : (i == 1) ? m1 : (i == 2) ? m2 : m3;
      base = atomicAdd(&cnt[i], __popcll(mi));
    }
    int mybase = __shfl(base, (myleaf < 0) ? 0 : myleaf);
    if (i < 32) list[myleaf * NROWS + mybase + rank] = myrow;
  }
}

// ---------------------------------------------------------------------------
#define BM 128
#define BN 128
#define BK 64
#define KSTEPS (NFEAT / BK)

__device__ __forceinline__ bool decode_tile(const int* cnt, int& leaf, int& mloc,
                                            int& ntile, int& cc) {
  int bid = blockIdx.x;
  int cpx = (int)(gridDim.x >> 3);
  int swz = (bid & 7) * cpx + (bid >> 3);
  int mtile = swz >> 2;
  ntile = swz & 3;
  int c0 = cnt[0], c1 = cnt[1], c2 = cnt[2], c3 = cnt[3];
  int t0 = (c0 + BM - 1) / BM, t1 = (c1 + BM - 1) / BM;
  int t2 = (c2 + BM - 1) / BM, t3 = (c3 + BM - 1) / BM;
  if (mtile < t0)                     { leaf = 0; mloc = mtile;                cc = c0; }
  else if (mtile < t0 + t1)           { leaf = 1; mloc = mtile - t0;           cc = c1; }
  else if (mtile < t0 + t1 + t2)      { leaf = 2; mloc = mtile - t0 - t1;      cc = c2; }
  else if (mtile < t0 + t1 + t2 + t3) { leaf = 3; mloc = mtile - t0 - t1 - t2; cc = c3; }
  else return false;
  return true;
}

// m97-structure grouped GEMM (unchanged from round 2 for A/B attribution).
__global__ __launch_bounds__(256) void gemm_lds_kernel(
    const __hip_bfloat16* __restrict__ xsb, const __hip_bfloat16* __restrict__ bt,
    const float* __restrict__ lb, const int* __restrict__ cnt,
    const int* __restrict__ list, float* __restrict__ out) {
  __shared__ __hip_bfloat16 Al[BM * BK];  // LDS[r][g] = A[row_r][g ^ (r&7)] (16B granules)
  __shared__ __hip_bfloat16 Bl[BN * BK];
  __shared__ int rows_s[BM];

  int leaf, mloc, ntile, cc;
  if (!decode_tile(cnt, leaf, mloc, ntile, cc)) return;

  const int tid = threadIdx.x;
  if (tid < BM) {
    int i = mloc * BM + tid;
    rows_s[tid] = (i < cc) ? list[leaf * NROWS + i] : -1;
  }
  __syncthreads();

  const int lane = tid & 63;
  const int wv = tid >> 6;
  const int g8 = (((lane & 7) ^ (lane >> 3)) << 3);  // inverse-swizzled src granule
  const __hip_bfloat16* asrc[4];
  const __hip_bfloat16* bsrc[4];
#pragma unroll
  for (int j = 0; j < 4; ++j) {
    int tr = wv * 32 + j * 8 + (lane >> 3);
    int grow = rows_s[tr];
    if (grow < 0) grow = 0;
    asrc[j] = xsb + (size_t)grow * NFEAT + g8;
    bsrc[j] = bt + ((size_t)leaf * NOUT + ntile * BN + tr) * NFEAT + g8;
  }

  const int wr = (wv >> 1) * 64;
  const int wc = (wv & 1) * 64;
  f32x4 acc[4][4];
#pragma unroll
  for (int m = 0; m < 4; ++m)
#pragma unroll
    for (int n = 0; n < 4; ++n) acc[m][n] = (f32x4){0.f, 0.f, 0.f, 0.f};

  for (int ks = 0; ks < KSTEPS; ++ks) {
    if (ks) __syncthreads();
#pragma unroll
    for (int j = 0; j < 4; ++j) {
      __builtin_amdgcn_global_load_lds(
          (const __attribute__((address_space(1))) void*)(asrc[j] + ks * BK),
          (__attribute__((address_space(3))) void*)(&Al[(wv * 4 + j) * 512]),
          16, 0, 0);
      __builtin_amdgcn_global_load_lds(
          (const __attribute__((address_space(1))) void*)(bsrc[j] + ks * BK),
          (__attribute__((address_space(3))) void*)(&Bl[(wv * 4 + j) * 512]),
          16, 0, 0);
    }
    __syncthreads();

#pragma unroll
    for (int kk = 0; kk < 2; ++kk) {
      bf16x8 af[4], bfr[4];
      int gk = kk * 4 + (lane >> 4);
#pragma unroll
      for (int m = 0; m < 4; ++m) {
        int r = wr + m * 16 + (lane & 15);
        af[m] = *(const bf16x8*)(&Al[r * BK + ((gk ^ (r & 7)) << 3)]);
      }
#pragma unroll
      for (int n = 0; n < 4; ++n) {
        int r = wc + n * 16 + (lane & 15);
        bfr[n] = *(const bf16x8*)(&Bl[r * BK + ((gk ^ (r & 7)) << 3)]);
      }
#pragma unroll
      for (int m = 0; m < 4; ++m)
#pragma unroll
        for (int n = 0; n < 4; ++n)
          acc[m][n] = __builtin_amdgcn_mfma_f32_16x16x32_bf16(
              af[m], bfr[n], acc[m][n], 0, 0, 0);
    }
  }

  int colb = ntile * BN + wc;
#pragma unroll
  for (int n = 0; n < 4; ++n) {
    int col = colb + n * 16 + (lane & 15);
    float bias = lb[leaf * NOUT + col];
#pragma unroll
    for (int m = 0; m < 4; ++m) {
#pragma unroll
      for (int r = 0; r < 4; ++r) {
        int lrow = wr + m * 16 + (lane >> 4) * 4 + r;
        int grow = rows_s[lrow];
        if (grow >= 0) out[(size_t)grow * NOUT + col] = acc[m][n][r] + bias;
      }
    }
  }
}

// ---------------------------------------------------------------------------
// Fallback GEMM (reg-staging, f32 A with on-the-fly cvt) for small ws.
__global__ __launch_bounds__(256) void gemm_fallback_kernel(
    const float* __restrict__ xs, const __hip_bfloat16* __restrict__ bt,
    const float* __restrict__ lb, const int* __restrict__ cnt,
    const int* __restrict__ list, float* __restrict__ out) {
  __shared__ __hip_bfloat16 Al[BM * BK];
  __shared__ __hip_bfloat16 Bl[BN * BK];
  __shared__ int rows_s[BM];

  int leaf, mloc, ntile, cc;
  if (!decode_tile(cnt, leaf, mloc, ntile, cc)) return;

  const int tid = threadIdx.x;
  if (tid < BM) {
    int i = mloc * BM + tid;
    rows_s[tid] = (i < cc) ? list[leaf * NROWS + i] : -1;
  }
  __syncthreads();

  const int srow = tid >> 1;
  const int shalf = tid & 1;
  int a_grow = rows_s[srow];
  int a_clamp = (a_grow < 0) ? 0 : a_grow;
  const float* aptr = xs + (size_t)a_clamp * NFEAT + shalf * 32;
  const __hip_bfloat16* bptr =
      bt + ((size_t)leaf * NOUT + ntile * BN + srow) * NFEAT + shalf * 32;

  const int lane = tid & 63;
  const int wv = tid >> 6;
  const int wr = (wv >> 1) * 64;
  const int wc = (wv & 1) * 64;

  f32x4 acc[4][4];
#pragma unroll
  for (int m = 0; m < 4; ++m)
#pragma unroll
    for (int n = 0; n < 4; ++n) acc[m][n] = (f32x4){0.f, 0.f, 0.f, 0.f};

  f32x4 av[8];
  bf16x8 bv[4];
#define LOAD_TILE(K0)                                                        \
  {                                                                          \
    _Pragma("unroll") for (int j = 0; j < 8; ++j)                            \
        av[j] = *(const f32x4*)(aptr + (K0) + j * 4);                        \
    _Pragma("unroll") for (int j = 0; j < 4; ++j)                            \
        bv[j] = *(const bf16x8*)(bptr + (K0) + j * 8);                       \
  }

  LOAD_TILE(0);

  for (int ks = 0; ks < KSTEPS; ++ks) {
#pragma unroll
    for (int j = 0; j < 4; ++j) {
      union { bf16x8 v; __hip_bfloat16 h[8]; } pk;
#pragma unroll
      for (int e = 0; e < 8; ++e)
        pk.h[e] = __float2bfloat16(av[j * 2 + (e >> 2)][e & 3]);
      int g = shalf * 4 + j;
      *(bf16x8*)(&Al[srow * BK + ((g ^ (srow & 7)) << 3)]) = pk.v;
    }
#pragma unroll
    for (int j = 0; j < 4; ++j) {
      int g = shalf * 4 + j;
      *(bf16x8*)(&Bl[srow * BK + ((g ^ (srow & 7)) << 3)]) = bv[j];
    }
    __syncthreads();

    if (ks + 1 < KSTEPS) LOAD_TILE((ks + 1) * BK);

#pragma unroll
    for (int kk = 0; kk < 2; ++kk) {
      bf16x8 af[4], bfr[4];
      int gk = kk * 4 + (lane >> 4);
#pragma unroll
      for (int m = 0; m < 4; ++m) {
        int r = wr + m * 16 + (lane & 15);
        af[m] = *(const bf16x8*)(&Al[r * BK + ((gk ^ (r & 7)) << 3)]);
      }
#pragma unroll
      for (int n = 0; n < 4; ++n) {
        int r = wc + n * 16 + (lane & 15);
        bfr[n] = *(const bf16x8*)(&Bl[r * BK + ((gk ^ (r & 7)) << 3)]);
      }
#pragma unroll
      for (int m = 0; m < 4; ++m)
#pragma unroll
        for (int n = 0; n < 4; ++n)
          acc[m][n] = __builtin_amdgcn_mfma_f32_16x16x32_bf16(
              af[m], bfr[n], acc[m][n], 0, 0, 0);
    }
    __syncthreads();
  }

  int colb = ntile * BN + wc;
#pragma unroll
  for (int n = 0; n < 4; ++n) {
    int col = colb + n * 16 + (lane & 15);
    float bias = lb[leaf * NOUT + col];
#pragma unroll
    for (int m = 0; m < 4; ++m) {
#pragma unroll
      for (int r = 0; r < 4; ++r) {
        int lrow = wr + m * 16 + (lane >> 4) * 4 + r;
        int grow = rows_s[lrow];
        if (grow >= 0) out[(size_t)grow * NOUT + col] = acc[m][n][r] + bias;
      }
    }
  }
}

// ---------------------------------------------------------------------------
extern "C" void kernel_launch(void* const* d_in, const int* in_sizes, int n_in,
                              void* d_out, int out_size, void* d_ws, size_t ws_size,
                              hipStream_t stream) {
  const float* xs = (const float*)d_in[0];
  const float* dw = (const float*)d_in[1];
  const float* db = (const float*)d_in[2];
  const float* lw = (const float*)d_in[3];
  const float* lb = (const float*)d_in[4];
  float* out = (float*)d_out;
  char* ws = (char*)d_ws;
  int* cnt = (int*)(ws + WS_CNT);
  int* list = (int*)(ws + WS_LIST);
  __hip_bfloat16* bt = (__hip_bfloat16*)(ws + WS_BT);
  bool big = ws_size >= WS_NEEDED;
  __hip_bfloat16* xsb = big ? (__hip_bfloat16*)(ws + WS_XB) : nullptr;

  zero_cnt_kernel<<<1, 64, 0, stream>>>(cnt);
  decide_tr_kernel<<<NDEC_BLOCKS + NTR_BLOCKS, 256, 0, stream>>>(
      xs, dw, db, lw, bt, cnt, list, xsb);
  // max M-tiles = sum ceil(cnt_k/128) <= 260; grid = 260*4 = 1040 = 8*130
  if (big)
    gemm_lds_kernel<<<1040, 256, 0, stream>>>(xsb, bt, lb, cnt, list, out);
  else
    gemm_fallback_kernel<<<1040, 256, 0, stream>>>(xs, bt, lb, cnt, list, out);
}